// Round 9
// baseline (395.698 us; speedup 1.0000x reference)
//
#include <hip/hip_runtime.h>
#include <hip/hip_bf16.h>

#define EMB 768
#define NHEADS 8
#define HDIM 96
#define SEQ 2048
#define BATCH 4
#define QKV_COLS 2304
#define PB ((size_t)SEQ * EMB)   // per-batch elements

typedef _Float16 f16;
typedef _Float16 f16x8 __attribute__((ext_vector_type(8)));
typedef _Float16 f16x4 __attribute__((ext_vector_type(4)));
typedef float f32x4 __attribute__((ext_vector_type(4)));

__device__ __forceinline__ void gl_lds16(const f16* g, f16* l) {
  __builtin_amdgcn_global_load_lds((const __attribute__((address_space(1))) void*)g,
                                   (__attribute__((address_space(3))) void*)l, 16, 0, 0);
}
__device__ __forceinline__ f32x4 vmax4(f32x4 a, f32x4 b) {
  f32x4 r;
  r[0] = fmaxf(a[0], b[0]); r[1] = fmaxf(a[1], b[1]);
  r[2] = fmaxf(a[2], b[2]); r[3] = fmaxf(a[3], b[3]);
  return r;
}

// ---------------- conversions ----------------
__global__ __launch_bounds__(256) void conv_x8_k(const float* __restrict__ in, size_t in_off,
                                                 f16* __restrict__ out, int n8) {
  int i = blockIdx.x * 256 + threadIdx.x;
  if (i >= n8) return;
  const float4 a = *(const float4*)(in + in_off + (size_t)i * 8);
  const float4 b = *(const float4*)(in + in_off + (size_t)i * 8 + 4);
  f16x8 o;
  o[0] = (f16)a.x; o[1] = (f16)a.y; o[2] = (f16)a.z; o[3] = (f16)a.w;
  o[4] = (f16)b.x; o[5] = (f16)b.y; o[6] = (f16)b.z; o[7] = (f16)b.w;
  *(f16x8*)(out + (size_t)i * 8) = o;
}

// qkv weight: transpose + column-permute. out[col'][r], col' = s*768+h*96+d.
__global__ __launch_bounds__(256) void wqkv_perm_k(const float* __restrict__ in,
                                                   f16* __restrict__ out) {
  int t = blockIdx.x * 256 + threadIdx.x;
  if (t >= QKV_COLS * (EMB / 8)) return;
  const int colp = t / (EMB / 8);
  const int r8 = (t - colp * (EMB / 8)) * 8;
  const int s = colp / 768, rem = colp - s * 768;
  const int h = rem / 96, d = rem - h * 96;
  const int c = h * 288 + d * 3 + s;
  f16x8 o;
#pragma unroll
  for (int i = 0; i < 8; i++) o[i] = (f16)in[(size_t)(r8 + i) * QKV_COLS + c];
  *(f16x8*)(out + (size_t)colp * EMB + r8) = o;
}

__global__ __launch_bounds__(256) void wproj_t_k(const float* __restrict__ in,
                                                 f16* __restrict__ out) {
  int t = blockIdx.x * 256 + threadIdx.x;
  if (t >= EMB * (EMB / 8)) return;
  const int cp = t / (EMB / 8);
  const int r8 = (t - cp * (EMB / 8)) * 8;
  f16x8 o;
#pragma unroll
  for (int i = 0; i < 8; i++) o[i] = (f16)in[(size_t)(r8 + i) * EMB + cp];
  *(f16x8*)(out + (size_t)cp * EMB + r8) = o;
}

__global__ __launch_bounds__(256) void bias_perm_k(const float* __restrict__ bq_in,
                                                   float* __restrict__ bq_out,
                                                   const float* __restrict__ bp_in,
                                                   float* __restrict__ bp_out) {
  int i = blockIdx.x * 256 + threadIdx.x;
  if (i < QKV_COLS) {
    const int s = i / 768, rem = i - s * 768;
    const int h = rem / 96, d = rem - h * 96;
    bq_out[i] = bq_in[h * 288 + d * 3 + s];
  }
  if (i < EMB) bp_out[i] = bp_in[i];
}

// ---------------- bt-GEMM (unchanged from R8) ----------------
template<int MODE>
__global__ __launch_bounds__(256) void gemm_bt(
    const f16* __restrict__ A, const f16* __restrict__ Bt,
    const float* __restrict__ bias, float* __restrict__ Cout,
    f16* __restrict__ QK, f16* __restrict__ Vt,
    int M, int N, int Kd)
{
  __shared__ f16 smem[MODE == 1 ? 17408 : 8192];
  f16* sA = smem;
  f16* sB = smem + 4096;
  const int tid  = threadIdx.x;
  const int wave = tid >> 6, lane = tid & 63;
  const int quad = lane >> 4, l16 = lane & 15;
  const int tile_m = blockIdx.y * 128, tile_n = blockIdx.x * 128;
  const int wm = (wave >> 1) * 64, wn = (wave & 1) * 64;

  f32x4 acc[4][4];
  for (int i = 0; i < 4; i++)
    for (int j = 0; j < 4; j++)
      acc[i][j] = f32x4{0.f, 0.f, 0.f, 0.f};

  for (int k0 = 0; k0 < Kd; k0 += 32) {
    __syncthreads();
#pragma unroll
    for (int it = 0; it < 2; it++) {
      const int ch  = (it * 4 + wave) * 64 + lane;
      const int row = ch >> 2, c8 = (ch & 3) * 8;
      gl_lds16(A  + (size_t)(tile_m + row) * Kd + k0 + c8, &sA[(it * 4 + wave) * 512]);
      gl_lds16(Bt + (size_t)(tile_n + row) * Kd + k0 + c8, &sB[(it * 4 + wave) * 512]);
    }
    __syncthreads();

    f16x8 af[4], bfr[4];
    for (int i = 0; i < 4; i++) af[i]  = *(const f16x8*)&sA[(wm + i * 16 + l16) * 32 + quad * 8];
    for (int j = 0; j < 4; j++) bfr[j] = *(const f16x8*)&sB[(wn + j * 16 + l16) * 32 + quad * 8];
    for (int i = 0; i < 4; i++)
      for (int j = 0; j < 4; j++)
        acc[i][j] = __builtin_amdgcn_mfma_f32_16x16x32_f16(af[i], bfr[j], acc[i][j], 0, 0, 0);
  }

  if (MODE == 1 && tile_n >= 1536) {
    __syncthreads();
    f16* sT = smem;    // [128][136]
    for (int j = 0; j < 4; j++) {
      const int cl = wn + j * 16 + l16;
      const float bv = bias[tile_n + cl];
      for (int i = 0; i < 4; i++)
        for (int r = 0; r < 4; r++)
          sT[cl * 136 + wm + i * 16 + quad * 4 + r] = (f16)(acc[i][j][r] + bv);
    }
    __syncthreads();
    const int bb = tile_m >> 11;
    const int n0 = tile_m & 2047;
#pragma unroll
    for (int l = 0; l < 8; l++) {
      const int cc = l * 256 + tid;
      const int rh = cc >> 4, nof = (cc & 15) * 8;
      const int hd = (tile_n - 1536) + rh;
      const int h = hd / 96, d = hd - h * 96;
      f16x8 v = *(const f16x8*)&sT[rh * 136 + nof];
      *(f16x8*)(Vt + ((size_t)(bb * NHEADS + h) * HDIM + d) * SEQ + n0 + nof) = v;
    }
  } else {
    for (int j = 0; j < 4; j++) {
      const int col = tile_n + wn + j * 16 + l16;
      const float bv = bias[col];
      for (int i = 0; i < 4; i++) {
        for (int r = 0; r < 4; r++) {
          const int row = tile_m + wm + i * 16 + quad * 4 + r;
          const float fv = acc[i][j][r] + bv;
          if (MODE == 0) Cout[(size_t)row * N + col] = fv;
          else           QK  [(size_t)row * 1536 + col] = (f16)fv;
        }
      }
    }
  }
}

// ---------------- flash attention (S^T scheme, union LDS) ----------------
// grid: (SEQ/128, nb*NHEADS); 4 waves; wave w owns q rows [w*32, w*32+32)
// QK mfma computes S^T (operands swapped): lane holds S[m=l16][n=jj*16+quad*4+r].
// Softmax: in-lane reduce + shfl_xor(16,32). P written as b64 to union buffer.
__global__ __launch_bounds__(256, 3) void attn_k(
    const f16* __restrict__ QK, const f16* __restrict__ Vt,
    f16* __restrict__ Out /* [nb,N,EMB] f16 */)
{
  __shared__ f16 sU[128 * 136];  // union: K-tile, then P; stride 136 (16B-aligned rows)
  const int tid  = threadIdx.x;
  const int wave = tid >> 6, lane = tid & 63;
  const int quad = lane >> 4, l16 = lane & 15;
  const int qt = blockIdx.x;
  const int bh = blockIdx.y;
  const int b = bh >> 3, h = bh & 7;

  const f16* Qb = QK + (size_t)(b * SEQ + qt * 128) * 1536 + h * 96;
  const f16* Kb = QK + (size_t)(b * SEQ) * 1536 + 768 + h * 96;
  const f16* Vb = Vt + (size_t)bh * HDIM * SEQ;

  // Q fragments (also valid as B-operand: lane -> col m=l16, k=quad*8+j)
  f16x8 qf[2][3];
  for (int ti = 0; ti < 2; ti++)
    for (int kc = 0; kc < 3; kc++)
      qf[ti][kc] = *(const f16x8*)(Qb + (size_t)(wave * 32 + ti * 16 + l16) * 1536 + kc * 32 + quad * 8);

  f32x4 oacc[2][6];
  for (int ti = 0; ti < 2; ti++)
    for (int dj = 0; dj < 6; dj++)
      oacc[ti][dj] = f32x4{0.f, 0.f, 0.f, 0.f};
  float m_run[2] = {-1e30f, -1e30f};
  float l_run[2] = {0.f, 0.f};

  for (int kt = 0; kt < SEQ / 128; kt++) {
    __syncthreads();   // (A) previous P reads done everywhere
    {
#pragma unroll
      for (int i = 0; i < 6; i++) {
        const int c = i * 256 + tid;            // 1536 chunks of 8 f16
        const int row = c / 12, col = (c % 12) * 8;
        *(uint4*)&sU[row * 136 + col] = *(const uint4*)(Kb + (size_t)(kt * 128 + row) * 1536 + col);
      }
    }
    __syncthreads();   // (B) K staged

    // ---- S^T = K * Q^T : sacc[ti][jj][r] = S[m=l16][n=jj*16+quad*4+r] ----
    f32x4 sacc[2][8];
    for (int ti = 0; ti < 2; ti++)
      for (int j = 0; j < 8; j++)
        sacc[ti][j] = f32x4{0.f, 0.f, 0.f, 0.f};
    for (int kc = 0; kc < 3; kc++) {
      for (int jj = 0; jj < 8; jj++) {
        f16x8 kf = *(const f16x8*)&sU[(jj * 16 + l16) * 136 + kc * 32 + quad * 8];
        sacc[0][jj] = __builtin_amdgcn_mfma_f32_16x16x32_f16(kf, qf[0][kc], sacc[0][jj], 0, 0, 0);
        sacc[1][jj] = __builtin_amdgcn_mfma_f32_16x16x32_f16(kf, qf[1][kc], sacc[1][jj], 0, 0, 0);
      }
    }
    __syncthreads();   // (C) all kf reads done -> safe to overwrite sU with P

    // ---- softmax (per ti; lane owns row m=l16) + P write ----
    for (int ti = 0; ti < 2; ti++) {
      f32x4 vm = sacc[ti][0];
      for (int jj = 1; jj < 8; jj++) vm = vmax4(vm, sacc[ti][jj]);
      float mx = fmaxf(fmaxf(vm[0], vm[1]), fmaxf(vm[2], vm[3]));
      mx = fmaxf(mx, __shfl_xor(mx, 16));
      mx = fmaxf(mx, __shfl_xor(mx, 32));
      const float nm = fmaxf(m_run[ti], mx);
      const float alpha = __expf(m_run[ti] - nm);
      m_run[ti] = nm;

      const int prow = wave * 32 + ti * 16 + l16;
      f32x4 rsv = f32x4{0.f, 0.f, 0.f, 0.f};
      for (int jj = 0; jj < 8; jj++) {
        f32x4 p;
        p[0] = __expf(sacc[ti][jj][0] - nm);
        p[1] = __expf(sacc[ti][jj][1] - nm);
        p[2] = __expf(sacc[ti][jj][2] - nm);
        p[3] = __expf(sacc[ti][jj][3] - nm);
        rsv += p;
        f16x4 pk;
        pk[0] = (f16)p[0]; pk[1] = (f16)p[1]; pk[2] = (f16)p[2]; pk[3] = (f16)p[3];
        *(f16x4*)&sU[prow * 136 + jj * 16 + quad * 4] = pk;
      }
      float rs = (rsv[0] + rsv[1]) + (rsv[2] + rsv[3]);
      rs += __shfl_xor(rs, 16);
      rs += __shfl_xor(rs, 32);
      l_run[ti] = l_run[ti] * alpha + rs;

      // rescale oacc rows (rows m = ti*16 + quad*4 + r; alpha lives at lane m)
      for (int r = 0; r < 4; r++) {
        const float ar = __shfl(alpha, quad * 4 + r);
        for (int dj = 0; dj < 6; dj++) oacc[ti][dj][r] *= ar;
      }
    }

    // ---- O += P @ Vtile ---- (P from own rows of sU; V direct global)
    for (int kc2 = 0; kc2 < 4; kc2++) {
      f16x8 pf0 = *(const f16x8*)&sU[(wave * 32 + 0 * 16 + l16) * 136 + kc2 * 32 + quad * 8];
      f16x8 pf1 = *(const f16x8*)&sU[(wave * 32 + 1 * 16 + l16) * 136 + kc2 * 32 + quad * 8];
      for (int dj = 0; dj < 6; dj++) {
        f16x8 vf = *(const f16x8*)(Vb + (size_t)(dj * 16 + l16) * SEQ + kt * 128 + kc2 * 32 + quad * 8);
        oacc[0][dj] = __builtin_amdgcn_mfma_f32_16x16x32_f16(pf0, vf, oacc[0][dj], 0, 0, 0);
        oacc[1][dj] = __builtin_amdgcn_mfma_f32_16x16x32_f16(pf1, vf, oacc[1][dj], 0, 0, 0);
      }
    }
  }

  const float inv_scale = 0.10206207261596577f;  // 1/sqrt(96), applied AFTER softmax per ref
  for (int ti = 0; ti < 2; ti++) {
    const float il = inv_scale / l_run[ti];
    for (int r = 0; r < 4; r++) {
      const float ilr = __shfl(il, quad * 4 + r);
      const int qrow = qt * 128 + wave * 32 + ti * 16 + quad * 4 + r;
      const size_t base = ((size_t)b * SEQ + qrow) * EMB + h * HDIM;
      for (int dj = 0; dj < 6; dj++) {
        Out[base + dj * 16 + l16] = (f16)(oacc[ti][dj][r] * ilr);
      }
    }
  }
}

// ---------------- launch ----------------
extern "C" void kernel_launch(void* const* d_in, const int* in_sizes, int n_in,
                              void* d_out, int out_size, void* d_ws, size_t ws_size,
                              hipStream_t stream) {
  const float* x      = (const float*)d_in[0];
  const float* w_qkv  = (const float*)d_in[1];
  const float* b_qkv  = (const float*)d_in[2];
  const float* w_proj = (const float*)d_in[3];
  const float* b_proj = (const float*)d_in[4];
  float* outF = (float*)d_out;   // fp32 output

  const size_t fixed = 256 + (size_t)QKV_COLS * EMB * 2 + (size_t)EMB * EMB * 2
                     + QKV_COLS * 4 + EMB * 4 + 256;
  const size_t perb = (size_t)4 * PB * 2;  // QK(2) + Vt(1) + attn(1) per batch
  int nb = (ws_size >= fixed + 4 * perb) ? 4 : (ws_size >= fixed + 2 * perb) ? 2 : 1;

  char* ws = (char*)d_ws;
  ws += 256;
  f16*   wqkvT  = (f16*)ws;   ws += (size_t)QKV_COLS * EMB * 2;
  f16*   wprojT = (f16*)ws;   ws += (size_t)EMB * EMB * 2;
  float* bq     = (float*)ws; ws += (size_t)QKV_COLS * 4;
  float* bp     = (float*)ws; ws += (size_t)EMB * 4 + 256;
  f16* QK   = (f16*)ws;       ws += (size_t)nb * 2 * PB * 2;   // [nb*2048][1536]
  f16* Vt   = (f16*)ws;       ws += (size_t)nb * PB * 2;       // [nb*8][96][2048]
  f16* attn = (f16*)ws;       ws += (size_t)nb * PB * 2;       // [nb][2048][768]

  wqkv_perm_k<<<(QKV_COLS * (EMB / 8) + 255) / 256, 256, 0, stream>>>(w_qkv, wqkvT);
  wproj_t_k<<<(EMB * (EMB / 8) + 255) / 256, 256, 0, stream>>>(w_proj, wprojT);
  bias_perm_k<<<(QKV_COLS + 255) / 256, 256, 0, stream>>>(b_qkv, bq, b_proj, bp);

  for (int outer = 0; outer < BATCH / nb; outer++) {
    const int bbase = outer * nb;
    const size_t goff = (size_t)bbase * PB;
    f16* xg = (f16*)(outF + goff);           // stage f16 x inside fp32 out region
    const int n8 = (int)((size_t)nb * PB / 8);
    conv_x8_k<<<(n8 + 255) / 256, 256, 0, stream>>>(x, goff, xg, n8);

    dim3 g1(QKV_COLS / 128, nb * SEQ / 128);
    gemm_bt<1><<<g1, 256, 0, stream>>>(xg, wqkvT, bq, nullptr, QK, Vt,
                                       nb * SEQ, QKV_COLS, EMB);

    dim3 g2(SEQ / 128, nb * NHEADS);
    attn_k<<<g2, 256, 0, stream>>>(QK, Vt, attn);

    dim3 g3(EMB / 128, nb * SEQ / 128);
    gemm_bt<0><<<g3, 256, 0, stream>>>(attn, wprojT, bp, outF + goff,
                                       nullptr, nullptr,
                                       nb * SEQ, EMB, EMB);
  }
}